// Round 1
// baseline (558.871 us; speedup 1.0000x reference)
//
#include <hip/hip_runtime.h>
#include <math.h>

typedef unsigned short u16;
typedef unsigned int u32;
typedef short s16x8 __attribute__((ext_vector_type(8)));
typedef float f32x4 __attribute__((ext_vector_type(4)));
typedef u16 u16x4 __attribute__((ext_vector_type(4)));

#define BM 128
#define BN 128
#define BK 64

__device__ __forceinline__ u16 f2bf(float x) {
  u32 u = __float_as_uint(x);
  u32 r = u + 0x7FFFu + ((u >> 16) & 1u);  // round-to-nearest-even
  return (u16)(r >> 16);
}
__device__ __forceinline__ float bf2f(u16 h) {
  return __uint_as_float(((u32)h) << 16);
}
__device__ __forceinline__ void splitbf(float x, u16 &hi, u16 &lo) {
  hi = f2bf(x);
  lo = f2bf(x - bf2f(hi));
}

__device__ __forceinline__ void gload16(const void* g, void* l) {
  __builtin_amdgcn_global_load_lds(
      (const __attribute__((address_space(1))) void*)g,
      (__attribute__((address_space(3))) void*)l, 16, 0, 0);
}

// ---------------------------------------------------------------------------
// NT GEMM: A [M,K] row-major (lda=K), B [N,K] row-major (ldb=K), C = A*B^T-ish
// i.e. C[m][n] = sum_k A[m][k]*B[n][k].  128x128 tile, BK=64, 4 waves (2x2),
// each wave 64x64 = 4x4 frags of 16x16, mfma_f32_16x16x32_bf16.
// LDS tiles [128][64] bf16 with XOR swizzle (slot16 ^= row&7); staging via
// global_load_lds (linear dest) reading pre-swizzled global source.
// EPI: 0=qkv split3-writer, 1=scores f32, 2=+resid f32, 3=+bias+gelu->bf16,
//      4=+bias+resid->f32 (final out)
// ---------------------------------------------------------------------------
template <int EPI>
__global__ __launch_bounds__(256, 2) void gemm_nt(
    const u16* __restrict__ A, const u16* __restrict__ B, int M, int N, int K,
    long zsA, long zsB, long zsC, float* __restrict__ outF,
    u16* __restrict__ outU, u16* __restrict__ outU2, u16* __restrict__ outU3,
    const float* __restrict__ aux0, const float* __restrict__ aux1) {
  __shared__ char smem[2 * BM * BK * 2];  // 32 KiB: sA | sB
  char* sA = smem;
  char* sB = smem + BM * BK * 2;

  const int tid = threadIdx.x;
  const int lane = tid & 63;
  const int wave = tid >> 6;
  const int z = blockIdx.z;
  const long row0 = (long)blockIdx.y * BM;
  const long col0 = (long)blockIdx.x * BN;

  const u16* Ab = A + (long)z * zsA;
  const u16* Bb = B + (long)z * zsB;

  // staging geometry: per call one wave covers 8 rows (8 lanes x 16B per row)
  const int srow = lane >> 3;               // row within 8-row chunk
  const int sslot = (lane & 7) ^ srow;      // pre-swizzled k-slot (16B units)

  const int wm = (wave >> 1) << 6;          // wave row offset in tile
  const int wn = (wave & 1) << 6;           // wave col offset in tile
  const int fr = lane & 15;
  const int kgrp = lane >> 4;

  f32x4 acc[4][4] = {};

  const int nk = K / BK;

  // prologue: stage k-tile 0
#pragma unroll
  for (int c = 0; c < 4; ++c) {
    const int chunk = wave * 4 + c;         // 0..15, 8 rows each
    const int r = chunk * 8 + srow;
    gload16(Ab + (row0 + r) * (long)K + sslot * 8, sA + chunk * 1024);
    gload16(Bb + (col0 + r) * (long)K + sslot * 8, sB + chunk * 1024);
  }

  for (int kt = 0; kt < nk; ++kt) {
    __syncthreads();  // compiler drains vmcnt(0) before s_barrier -> LDS ready
#pragma unroll
    for (int kk = 0; kk < 2; ++kk) {
      s16x8 af[4], bg[4];
#pragma unroll
      for (int i = 0; i < 4; ++i) {
        const int r = wm + i * 16 + fr;
        const int slot = ((kk << 2) | kgrp) ^ (r & 7);
        af[i] = *(const s16x8*)(sA + r * 128 + slot * 16);
      }
#pragma unroll
      for (int j = 0; j < 4; ++j) {
        const int r = wn + j * 16 + fr;
        const int slot = ((kk << 2) | kgrp) ^ (r & 7);
        bg[j] = *(const s16x8*)(sB + r * 128 + slot * 16);
      }
#pragma unroll
      for (int i = 0; i < 4; ++i)
#pragma unroll
        for (int j = 0; j < 4; ++j)
          acc[i][j] = __builtin_amdgcn_mfma_f32_16x16x32_bf16(af[i], bg[j],
                                                              acc[i][j], 0, 0, 0);
    }
    __syncthreads();  // all waves done reading this tile
    if (kt + 1 < nk) {
      const long k0 = (long)(kt + 1) * BK;
#pragma unroll
      for (int c = 0; c < 4; ++c) {
        const int chunk = wave * 4 + c;
        const int r = chunk * 8 + srow;
        gload16(Ab + (row0 + r) * (long)K + k0 + sslot * 8, sA + chunk * 1024);
        gload16(Bb + (col0 + r) * (long)K + k0 + sslot * 8, sB + chunk * 1024);
      }
    }
  }

  // epilogue: C/D frag layout (verified): col = lane&15, row = (lane>>4)*4 + r
#pragma unroll
  for (int i = 0; i < 4; ++i) {
#pragma unroll
    for (int j = 0; j < 4; ++j) {
#pragma unroll
      for (int r = 0; r < 4; ++r) {
        const long m = row0 + wm + i * 16 + (kgrp << 2) + r;
        const long n = col0 + wn + j * 16 + fr;
        const float val = acc[i][j][r];
        if constexpr (EPI == 0) {
          // qkv: n<1024 -> q3 (hi,lo,hi); n<2048 -> k3 (hi,hi,lo); else v bf16
          if (n < 1024) {
            u16 hi, lo; splitbf(val, hi, lo);
            u16* p = outU + m * 3072 + n;
            p[0] = hi; p[1024] = lo; p[2048] = hi;
          } else if (n < 2048) {
            u16 hi, lo; splitbf(val, hi, lo);
            u16* p = outU2 + m * 3072 + (n - 1024);
            p[0] = hi; p[1024] = hi; p[2048] = lo;
          } else {
            outU3[m * 1024 + (n - 2048)] = f2bf(val);
          }
        } else if constexpr (EPI == 1) {
          outF[(long)z * zsC + m * (long)N + n] = val;
        } else if constexpr (EPI == 2) {
          const long idx = (long)z * zsC + m * (long)N + n;
          outF[idx] = val + aux0[idx];
        } else if constexpr (EPI == 3) {
          const float t = val + aux0[n];
          const float gl = 0.5f * t * (1.0f + erff(t * 0.70710678118654752f));
          outU[m * (long)N + n] = f2bf(gl);
        } else {
          outF[m * (long)N + n] = val + aux0[n] + aux1[m * (long)N + n];
        }
      }
    }
  }
}

// ---------------------------------------------------------------------------
// LayerNorm over D=1024, one wave per row, 4 rows/block.
// SPLIT3: write [row][3072] = (hi | lo | hi) tripled-K operand for split GEMM.
// else:   write [row][1024] plain bf16.
// ---------------------------------------------------------------------------
template <bool SPLIT3>
__global__ __launch_bounds__(256) void ln_k(const float* __restrict__ x,
                                            const float* __restrict__ gw,
                                            const float* __restrict__ bw,
                                            u16* __restrict__ out) {
  const int lane = threadIdx.x & 63;
  const int wv = threadIdx.x >> 6;
  const long row = (long)blockIdx.x * 4 + wv;
  const float* xr = x + row * 1024;
  float4 v[4];
  float s = 0.f, ss = 0.f;
#pragma unroll
  for (int j = 0; j < 4; ++j) {
    v[j] = *(const float4*)(xr + (lane + 64 * j) * 4);
    s += v[j].x + v[j].y + v[j].z + v[j].w;
    ss += v[j].x * v[j].x + v[j].y * v[j].y + v[j].z * v[j].z + v[j].w * v[j].w;
  }
#pragma unroll
  for (int o = 32; o; o >>= 1) {
    s += __shfl_xor(s, o);
    ss += __shfl_xor(ss, o);
  }
  const float mu = s * (1.f / 1024.f);
  const float var = ss * (1.f / 1024.f) - mu * mu;
  const float rs = rsqrtf(var + 1e-5f);
  u16* orow = out + row * (SPLIT3 ? 3072 : 1024);
#pragma unroll
  for (int j = 0; j < 4; ++j) {
    const int n = (lane + 64 * j) * 4;
    const float4 gg = *(const float4*)(gw + n);
    const float4 bb = *(const float4*)(bw + n);
    const float y[4] = {(v[j].x - mu) * rs * gg.x + bb.x,
                        (v[j].y - mu) * rs * gg.y + bb.y,
                        (v[j].z - mu) * rs * gg.z + bb.z,
                        (v[j].w - mu) * rs * gg.w + bb.w};
    u16x4 H, L;
#pragma unroll
    for (int c = 0; c < 4; ++c) {
      u16 hi, lo; splitbf(y[c], hi, lo);
      H[c] = hi; L[c] = lo;
    }
    if constexpr (SPLIT3) {
      *(u16x4*)(orow + n) = H;
      *(u16x4*)(orow + 1024 + n) = L;
      *(u16x4*)(orow + 2048 + n) = H;
    } else {
      *(u16x4*)(orow + n) = H;
    }
  }
}

// ---------------------------------------------------------------------------
// Tiled transpose+convert. in [R,C] -> out [C,R] (per z).
// MODE 0: f32 -> bf16; MODE 1: f32 -> split3 [C,3R] = (hi|hi|lo) B3-operand;
// MODE 2: bf16 -> bf16.
// ---------------------------------------------------------------------------
template <int MODE>
__global__ __launch_bounds__(256) void transpose_k(const void* __restrict__ in,
                                                   u16* __restrict__ out, int R,
                                                   int C, long zsIn, long zsOut) {
  __shared__ float tile[32][33];
  const int z = blockIdx.z;
  const int c0 = blockIdx.x * 32, r0 = blockIdx.y * 32;
#pragma unroll
  for (int i = 0; i < 4; ++i) {
    const int lin = threadIdx.x + 256 * i;
    const int rr = lin >> 5, cc = lin & 31;
    float vv;
    if constexpr (MODE == 2)
      vv = bf2f(((const u16*)in + (long)z * zsIn)[(long)(r0 + rr) * C + c0 + cc]);
    else
      vv = ((const float*)in)[(long)(r0 + rr) * C + c0 + cc];
    tile[rr][cc] = vv;
  }
  __syncthreads();
  u16* outz = out + (long)z * zsOut;
#pragma unroll
  for (int i = 0; i < 4; ++i) {
    const int lin = threadIdx.x + 256 * i;
    const int oc = lin >> 5, orr = lin & 31;
    const float vv = tile[orr][oc];
    if constexpr (MODE == 1) {
      u16 hi, lo; splitbf(vv, hi, lo);
      u16* p = out + (long)(c0 + oc) * (3L * R) + (r0 + orr);
      p[0] = hi; p[R] = hi; p[2 * R] = lo;
    } else {
      outz[(long)(c0 + oc) * R + (r0 + orr)] = f2bf(vv);
    }
  }
}

// ---------------------------------------------------------------------------
// Row softmax over 2048 cols, f32 in -> bf16 out. One block (256 thr) per row.
// ---------------------------------------------------------------------------
__global__ __launch_bounds__(256) void softmax_k(const float* __restrict__ S,
                                                 u16* __restrict__ P) {
  const long row = blockIdx.x;
  const float* sr = S + row * 2048;
  u16* pr = P + row * 2048;
  const int tid = threadIdx.x;
  const int lane = tid & 63, wv = tid >> 6;
  __shared__ float red[8];
  const float4 v0 = *(const float4*)(sr + tid * 4);
  const float4 v1 = *(const float4*)(sr + 1024 + tid * 4);
  float mx = fmaxf(fmaxf(fmaxf(v0.x, v0.y), fmaxf(v0.z, v0.w)),
                   fmaxf(fmaxf(v1.x, v1.y), fmaxf(v1.z, v1.w)));
#pragma unroll
  for (int o = 32; o; o >>= 1) mx = fmaxf(mx, __shfl_xor(mx, o));
  if (lane == 0) red[wv] = mx;
  __syncthreads();
  mx = fmaxf(fmaxf(red[0], red[1]), fmaxf(red[2], red[3]));
  float e[8];
  e[0] = expf(v0.x - mx); e[1] = expf(v0.y - mx);
  e[2] = expf(v0.z - mx); e[3] = expf(v0.w - mx);
  e[4] = expf(v1.x - mx); e[5] = expf(v1.y - mx);
  e[6] = expf(v1.z - mx); e[7] = expf(v1.w - mx);
  float sm = e[0] + e[1] + e[2] + e[3] + e[4] + e[5] + e[6] + e[7];
#pragma unroll
  for (int o = 32; o; o >>= 1) sm += __shfl_xor(sm, o);
  if (lane == 0) red[4 + wv] = sm;
  __syncthreads();
  sm = red[4] + red[5] + red[6] + red[7];
  const float inv = 1.f / sm;
  u16x4 a, b;
  a[0] = f2bf(e[0] * inv); a[1] = f2bf(e[1] * inv);
  a[2] = f2bf(e[2] * inv); a[3] = f2bf(e[3] * inv);
  b[0] = f2bf(e[4] * inv); b[1] = f2bf(e[5] * inv);
  b[2] = f2bf(e[6] * inv); b[3] = f2bf(e[7] * inv);
  *(u16x4*)(pr + tid * 4) = a;
  *(u16x4*)(pr + 1024 + tid * 4) = b;
}

// ---------------------------------------------------------------------------
extern "C" void kernel_launch(void* const* d_in, const int* in_sizes, int n_in,
                              void* d_out, int out_size, void* d_ws,
                              size_t ws_size, hipStream_t stream) {
  const float* x      = (const float*)d_in[0];  // [4,2048,1024]
  const float* w_qkv  = (const float*)d_in[1];  // [1024,3072]
  const float* fc1_w  = (const float*)d_in[2];  // [1024,4096]
  const float* fc1_b  = (const float*)d_in[3];  // [4096]
  const float* fc2_w  = (const float*)d_in[4];  // [4096,1024]
  const float* fc2_b  = (const float*)d_in[5];  // [1024]
  const float* ln1_g  = (const float*)d_in[6];
  const float* ln1_b  = (const float*)d_in[7];
  const float* ln2_g  = (const float*)d_in[8];
  const float* ln2_b  = (const float*)d_in[9];
  float* out = (float*)d_out;

  // workspace layout (phase-aliased; peak 178 MB)
  char* ws = (char*)d_ws;
  const long MB = 1024L * 1024L;
  u16*   h3   = (u16*)(ws + 0);         // 48MB [8192,3072] (hi|lo|hi)
  u16*   wq3  = (u16*)(ws + 48 * MB);   // 18MB [3072,3072] (hi|hi|lo)
  u16*   q3   = (u16*)(ws + 66 * MB);   // 48MB
  u16*   k3   = (u16*)(ws + 114 * MB);  // 48MB
  u16*   vbuf = (u16*)(ws + 162 * MB);  // 16MB [8192,1024]
  float* sc   = (float*)(ws + 0);       // 64MB scores (h3/wq3 dead)
  u16*   P    = (u16*)(ws + 64 * MB);   // 32MB (q3 dead after GEMM2)
  u16*   vT   = (u16*)(ws + 96 * MB);   // 16MB [4][1024][2048]
  float* r2   = (float*)(ws + 112 * MB);// 32MB (k3 dead)
  u16*   h2   = (u16*)(ws + 144 * MB);  // 16MB
  u16*   w1T  = (u16*)(ws + 160 * MB);  //  8MB [4096,1024]
  u16*   w2T  = (u16*)(ws + 168 * MB);  //  8MB [1024,4096]
  u16*   g    = (u16*)(ws + 0);         // 64MB [8192,4096] (scores dead)

  dim3 blk(256);

  // 1) LN1 -> h3 (split3 A-operand)
  ln_k<true><<<2048, blk, 0, stream>>>(x, ln1_g, ln1_b, h3);
  // 2) w_qkv [1024,3072] -> wq3 [3072,3072] (split3 B-operand)
  transpose_k<1><<<dim3(3072 / 32, 1024 / 32, 1), blk, 0, stream>>>(
      w_qkv, wq3, 1024, 3072, 0, 0);
  // 3) GEMM1 (emulated-fp32): qkv = h @ w_qkv -> q3,k3,v
  gemm_nt<0><<<dim3(3072 / BN, 8192 / BM, 1), blk, 0, stream>>>(
      h3, wq3, 8192, 3072, 3072, 0, 0, 0, nullptr, q3, k3, vbuf, nullptr,
      nullptr);
  // 4) GEMM2 (emulated-fp32): scores[b] = q[b] @ k[b]^T
  gemm_nt<1><<<dim3(2048 / BN, 2048 / BM, 4), blk, 0, stream>>>(
      q3, k3, 2048, 2048, 3072, 2048L * 3072, 2048L * 3072, 2048L * 2048, sc,
      nullptr, nullptr, nullptr, nullptr, nullptr);
  // 5) v [b][2048,1024] -> vT [b][1024,2048]
  transpose_k<2><<<dim3(1024 / 32, 2048 / 32, 4), blk, 0, stream>>>(
      vbuf, vT, 2048, 1024, 2048L * 1024, 1024L * 2048);
  // 6) softmax rows -> P bf16
  softmax_k<<<8192, blk, 0, stream>>>(sc, P);
  // 7) GEMM3: attn[b] = P[b] @ v[b]; += residual x -> r2
  gemm_nt<2><<<dim3(1024 / BN, 2048 / BM, 4), blk, 0, stream>>>(
      P, vT, 2048, 1024, 2048, 2048L * 2048, 1024L * 2048, 2048L * 1024, r2,
      nullptr, nullptr, nullptr, x, nullptr);
  // 8) LN2 -> h2 bf16
  ln_k<false><<<2048, blk, 0, stream>>>(r2, ln2_g, ln2_b, h2);
  // 9) fc1_w [1024,4096] -> w1T [4096,1024] bf16
  transpose_k<0><<<dim3(4096 / 32, 1024 / 32, 1), blk, 0, stream>>>(
      fc1_w, w1T, 1024, 4096, 0, 0);
  // 10) fc2_w [4096,1024] -> w2T [1024,4096] bf16
  transpose_k<0><<<dim3(1024 / 32, 4096 / 32, 1), blk, 0, stream>>>(
      fc2_w, w2T, 4096, 1024, 0, 0);
  // 11) GEMM4: g = gelu(h2 @ fc1_w + b1) bf16
  gemm_nt<3><<<dim3(4096 / BN, 8192 / BM, 1), blk, 0, stream>>>(
      h2, w1T, 8192, 4096, 1024, 0, 0, 0, nullptr, g, nullptr, nullptr, fc1_b,
      nullptr);
  // 12) GEMM5: out = g @ fc2_w + b2 + r2
  gemm_nt<4><<<dim3(1024 / BN, 8192 / BM, 1), blk, 0, stream>>>(
      g, w2T, 8192, 1024, 4096, 0, 0, 0, out, nullptr, nullptr, nullptr, fc2_b,
      r2);
}